// Round 2
// baseline (13.671 us; speedup 1.0000x reference)
//
#include <hip/hip_runtime.h>

// CenterPixelMSE: out = mean_b (pred[b,0,centers[b,0],centers[b,1]] - target[b])^2
// B=512, H=W=256. Pure gather + tiny reduction -> launch/latency bound.
// Single-wave version: 64 lanes x 8 batch elems each, all 512 gathers in
// flight at once, no LDS / no __syncthreads, one 6-step shuffle reduce.

#define B_SIZE 512
#define H_DIM 256
#define W_DIM 256

__global__ __launch_bounds__(64) void center_mse_kernel(
    const float* __restrict__ pred,
    const float* __restrict__ target,
    const int* __restrict__ centers,
    float* __restrict__ out)
{
    const int l = threadIdx.x;      // 0..63
    const int b0 = l * 8;           // each lane owns batches [b0, b0+8)

    // centers for 8 batches: 16 ints = 4 x int4 (contiguous 32B per lane)
    const int4* c4 = (const int4*)(centers + 2 * b0);
    int4 ca = c4[0];
    int4 cb = c4[1];
    int4 cc = c4[2];
    int4 cd = c4[3];

    // targets for 8 batches: 2 x float4
    const float4* t4 = (const float4*)(target + b0);
    float4 ta = t4[0];
    float4 tb = t4[1];

    int r[8], c[8];
    r[0] = ca.x; c[0] = ca.y;  r[1] = ca.z; c[1] = ca.w;
    r[2] = cb.x; c[2] = cb.y;  r[3] = cb.z; c[3] = cb.w;
    r[4] = cc.x; c[4] = cc.y;  r[5] = cc.z; c[5] = cc.w;
    r[6] = cd.x; c[6] = cd.y;  r[7] = cd.z; c[7] = cd.w;

    float t[8] = { ta.x, ta.y, ta.z, ta.w, tb.x, tb.y, tb.z, tb.w };

    // 8 independent gathers per lane — compiler issues all before waiting.
    float p[8];
    #pragma unroll
    for (int k = 0; k < 8; ++k) {
        p[k] = pred[(size_t)(b0 + k) * (H_DIM * W_DIM) + r[k] * W_DIM + c[k]];
    }

    float v = 0.0f;
    #pragma unroll
    for (int k = 0; k < 8; ++k) {
        const float d = p[k] - t[k];
        v += d * d;
    }

    // Wave-64 butterfly reduce
    #pragma unroll
    for (int off = 32; off > 0; off >>= 1) {
        v += __shfl_down(v, off, 64);
    }

    if (l == 0) out[0] = v * (1.0f / (float)B_SIZE);
}

extern "C" void kernel_launch(void* const* d_in, const int* in_sizes, int n_in,
                              void* d_out, int out_size, void* d_ws, size_t ws_size,
                              hipStream_t stream) {
    const float* pred    = (const float*)d_in[0];
    const float* target  = (const float*)d_in[1];
    const int*   centers = (const int*)d_in[2];
    float* out = (float*)d_out;

    center_mse_kernel<<<1, 64, 0, stream>>>(pred, target, centers, out);
}

// Round 3
// 11.688 us; speedup vs baseline: 1.1697x; 1.1697x over previous
//
#include <hip/hip_runtime.h>

// CenterPixelMSE: out = mean_b (pred[b,0,centers[b,0],centers[b,1]] - target[b])^2
// B=512, H=W=256. ~8 KB of useful reads total -> pure launch/latency bound.
// 512 threads / 8 waves: all gathers issued concurrently across 4 SIMDs.

#define B_SIZE 512
#define H_DIM 256
#define W_DIM 256

__global__ __launch_bounds__(B_SIZE) void center_mse_kernel(
    const float* __restrict__ pred,
    const float* __restrict__ target,
    const int* __restrict__ centers,
    float* __restrict__ out)
{
    const int b = threadIdx.x;  // 0..511, one thread per batch element

    // Coalesced 8B load of (row, col) per thread
    const int2 rc = ((const int2*)centers)[b];
    const float t = target[b];
    const float p = pred[(size_t)b * (H_DIM * W_DIM) + rc.x * W_DIM + rc.y];
    const float d = p - t;
    float v = d * d;

    // Wave-64 reduction
    #pragma unroll
    for (int off = 32; off > 0; off >>= 1) {
        v += __shfl_down(v, off, 64);
    }

    // 8 wave partials -> LDS -> final reduce by wave 0
    __shared__ float partials[B_SIZE / 64];
    const int wave = b >> 6;
    const int lane = b & 63;
    if (lane == 0) partials[wave] = v;
    __syncthreads();

    if (wave == 0) {
        float s = (lane < (B_SIZE / 64)) ? partials[lane] : 0.0f;
        #pragma unroll
        for (int off = 4; off > 0; off >>= 1) {
            s += __shfl_down(s, off, 64);
        }
        if (lane == 0) out[0] = s * (1.0f / (float)B_SIZE);
    }
}

extern "C" void kernel_launch(void* const* d_in, const int* in_sizes, int n_in,
                              void* d_out, int out_size, void* d_ws, size_t ws_size,
                              hipStream_t stream) {
    const float* pred    = (const float*)d_in[0];
    const float* target  = (const float*)d_in[1];
    const int*   centers = (const int*)d_in[2];
    float* out = (float*)d_out;

    center_mse_kernel<<<1, B_SIZE, 0, stream>>>(pred, target, centers, out);
}